// Round 4
// baseline (229.484 us; speedup 1.0000x reference)
//
#include <hip/hip_runtime.h>

// PatternAwareLoss, single fused kernel (last-block-done finalize).
// B=64, S=8192, L=24. Blocks of 256 threads handle 256 consecutive positions
// (1536 float4/int4 chunks, perfectly coalesced). 8192/256 = 32 blocks/row,
// so row boundaries align with block boundaries.
constexpr int Bdim = 64;
constexpr int S = 8192;
constexpr int L = 24;
constexpr int NPOS = Bdim * S;            // 524288
constexpr int POS_PER_BLK = 256;
constexpr int NBLK = NPOS / POS_PER_BLK;  // 2048
constexpr int BLK_PER_ROW = S / POS_PER_BLK; // 32
constexpr float BOOST = 1.2f;

__device__ __forceinline__ float bce(float x, float y) {
    // max(x,0) - x*y + log1p(exp(-|x|)) with HW transcendentals.
    // arg of __logf is in (1,2]: relative err ~1e-7, final-scalar impact ~1e-6
    // vs 0.465 tolerance.
    float e = __expf(-fabsf(x));
    float l = __logf(1.0f + e);
    return fmaxf(x, 0.0f) - x * y + l;
}

__global__ __launch_bounds__(256) void pal_main(
    const float* __restrict__ logits,
    const int*   __restrict__ labels,
    const float* __restrict__ mask,
    double*       __restrict__ partials,   // [2 * NBLK]
    unsigned int* __restrict__ counter,    // zeroed each launch
    float*        __restrict__ out)
{
    __shared__ float psum[1536];
    __shared__ float plab[1536];
    __shared__ unsigned char hp_next_sh;   // has_punct of position base+256
    __shared__ float wl[4], wm[4];
    __shared__ int   is_last_sh;

    const int t = threadIdx.x;
    const size_t cbase = (size_t)blockIdx.x * 1536;   // chunk base (16B chunks)

    // t==0 peeks next block's first position (96 B) for the boundary boost;
    // forced 0 on the last block of a row (s==S-1 never boosts).
    if (t == 0) {
        int hn = 0;
        if ((blockIdx.x & (BLK_PER_ROW - 1)) != BLK_PER_ROW - 1) {
            const int4* nb = (const int4*)labels + cbase + 1536;
            int sn = 0;
#pragma unroll
            for (int j = 0; j < 6; ++j) { int4 v = nb[j]; sn += v.x + v.y + v.z + v.w; }
            hn = (sn > 0) ? 1 : 0;
        }
        hp_next_sh = (unsigned char)hn;
    }

#pragma unroll
    for (int k = 0; k < 6; ++k) {
        const size_t c = cbase + (size_t)t + 256 * k;
        float4 lg = ((const float4*)logits)[c];
        int4   lb = ((const int4*)labels)[c];
        float s = 0.0f;
        s += bce(lg.x, (float)lb.x);
        s += bce(lg.y, (float)lb.y);
        s += bce(lg.z, (float)lb.z);
        s += bce(lg.w, (float)lb.w);
        psum[t + 256 * k] = s;
        plab[t + 256 * k] = (float)(lb.x + lb.y + lb.z + lb.w);
    }
    __syncthreads();

    // phase 2: one position per thread (stride-6 LDS reads: 2-way bank alias, free)
    float ls = 0.0f, lab = 0.0f;
#pragma unroll
    for (int j = 0; j < 6; ++j) { ls += psum[6 * t + j]; lab += plab[6 * t + j]; }
    const int hp = (lab > 0.0f);
    int hpn;
    if (t < POS_PER_BLK - 1) {
        float ln = 0.0f;
#pragma unroll
        for (int j = 0; j < 6; ++j) ln += plab[6 * t + 6 + j];
        hpn = (ln > 0.0f);
    } else {
        hpn = hp_next_sh;
    }
    const float boost = (hp && hpn) ? BOOST : 1.0f;
    float m = mask[(size_t)blockIdx.x * POS_PER_BLK + t];
    float contrib = ls * boost * m;

    // block reduction: wave shuffles, thread 0 folds 4 wave sums
#pragma unroll
    for (int off = 32; off > 0; off >>= 1) {
        contrib += __shfl_down(contrib, off, 64);
        m       += __shfl_down(m, off, 64);
    }
    if ((t & 63) == 0) { wl[t >> 6] = contrib; wm[t >> 6] = m; }
    __syncthreads();

    if (t == 0) {
        double Ls = (double)wl[0] + (double)wl[1] + (double)wl[2] + (double)wl[3];
        double Ms = (double)wm[0] + (double)wm[1] + (double)wm[2] + (double)wm[3];
        partials[2 * blockIdx.x]     = Ls;
        partials[2 * blockIdx.x + 1] = Ms;
        __threadfence();   // device-scope release of the partial
        unsigned int prev = __hip_atomic_fetch_add(counter, 1u,
                                __ATOMIC_ACQ_REL, __HIP_MEMORY_SCOPE_AGENT);
        is_last_sh = (prev == NBLK - 1);
    }
    __syncthreads();

    // last block to finish reduces all partials (deterministic order)
    if (is_last_sh) {
        double l = 0.0, mm = 0.0;
        for (int i = t; i < NBLK; i += 256) {
            l  += __hip_atomic_load(&partials[2 * i],     __ATOMIC_RELAXED,
                                    __HIP_MEMORY_SCOPE_AGENT);
            mm += __hip_atomic_load(&partials[2 * i + 1], __ATOMIC_RELAXED,
                                    __HIP_MEMORY_SCOPE_AGENT);
        }
        __shared__ double sl[256], sm[256];
        sl[t] = l; sm[t] = mm;
        __syncthreads();
        for (int off = 128; off > 0; off >>= 1) {
            if (t < off) { sl[t] += sl[t + off]; sm[t] += sm[t + off]; }
            __syncthreads();
        }
        if (t == 0) out[0] = (float)(sl[0] / sm[0]);
    }
}

extern "C" void kernel_launch(void* const* d_in, const int* in_sizes, int n_in,
                              void* d_out, int out_size, void* d_ws, size_t ws_size,
                              hipStream_t stream) {
    const float* logits = (const float*)d_in[0];
    const int*   labels = (const int*)d_in[1];
    const float* mask   = (const float*)d_in[2];
    float* out = (float*)d_out;

    // ws: partials (2*NBLK f64 = 32 KB) | counter (u32)
    double*       partials = (double*)d_ws;
    unsigned int* counter  = (unsigned int*)((char*)d_ws + 2 * NBLK * sizeof(double));

    hipMemsetAsync(counter, 0, sizeof(unsigned int), stream);
    pal_main<<<NBLK, 256, 0, stream>>>(logits, labels, mask, partials, counter, out);
}

// Round 5
// 121.965 us; speedup vs baseline: 1.8816x; 1.8816x over previous
//
#include <hip/hip_runtime.h>

// PatternAwareLoss — two-kernel structure (fences/atomics proved 20x more
// expensive than a second launch on CDNA4: R4 post-mortem).
// B=64, S=8192, L=24. Blocks of 256 threads handle 256 consecutive positions
// (1536 float4/int4 chunks, perfectly coalesced). 8192/256 = 32 blocks/row,
// so row boundaries align with block boundaries.
constexpr int Bdim = 64;
constexpr int S = 8192;
constexpr int L = 24;
constexpr int NPOS = Bdim * S;            // 524288
constexpr int POS_PER_BLK = 256;
constexpr int NBLK = NPOS / POS_PER_BLK;  // 2048
constexpr int BLK_PER_ROW = S / POS_PER_BLK; // 32
constexpr float BOOST = 1.2f;

__device__ __forceinline__ float bce(float x, float y) {
    // max(x,0) - x*y + log1p(exp(-|x|)) with HW transcendentals.
    // __logf arg in (1,2]: rel err ~1e-7; final-scalar impact ~1e-6 vs 0.465 tol.
    float e = __expf(-fabsf(x));
    float l = __logf(1.0f + e);
    return fmaxf(x, 0.0f) - x * y + l;
}

__global__ __launch_bounds__(256) void pal_main(
    const float* __restrict__ logits,
    const int*   __restrict__ labels,
    const float* __restrict__ mask,
    double*      __restrict__ partials)   // [2 * NBLK]
{
    __shared__ float psum[1536];
    __shared__ float plab[1536];
    __shared__ unsigned char hp_next_sh;   // has_punct of position base+256
    __shared__ float wl[4], wm[4];

    const int t = threadIdx.x;
    const size_t cbase = (size_t)blockIdx.x * 1536;   // 16B-chunk base

    // t==0 peeks next block's first position (96 B) for the boundary boost;
    // forced 0 on the last block of a row (s==S-1 never boosts).
    if (t == 0) {
        int hn = 0;
        if ((blockIdx.x & (BLK_PER_ROW - 1)) != BLK_PER_ROW - 1) {
            const int4* nb = (const int4*)labels + cbase + 1536;
            int sn = 0;
#pragma unroll
            for (int j = 0; j < 6; ++j) { int4 v = nb[j]; sn += v.x + v.y + v.z + v.w; }
            hn = (sn > 0) ? 1 : 0;
        }
        hp_next_sh = (unsigned char)hn;
    }

#pragma unroll
    for (int k = 0; k < 6; ++k) {
        const size_t c = cbase + (size_t)t + 256 * k;
        float4 lg = ((const float4*)logits)[c];
        int4   lb = ((const int4*)labels)[c];
        float s = 0.0f;
        s += bce(lg.x, (float)lb.x);
        s += bce(lg.y, (float)lb.y);
        s += bce(lg.z, (float)lb.z);
        s += bce(lg.w, (float)lb.w);
        psum[t + 256 * k] = s;
        plab[t + 256 * k] = (float)(lb.x + lb.y + lb.z + lb.w);
    }
    __syncthreads();

    // phase 2: one position per thread — all 256 threads active
    float ls = 0.0f, lab = 0.0f;
#pragma unroll
    for (int j = 0; j < 6; ++j) { ls += psum[6 * t + j]; lab += plab[6 * t + j]; }
    const int hp = (lab > 0.0f);
    int hpn;
    if (t < POS_PER_BLK - 1) {
        float ln = 0.0f;
#pragma unroll
        for (int j = 0; j < 6; ++j) ln += plab[6 * t + 6 + j];
        hpn = (ln > 0.0f);
    } else {
        hpn = hp_next_sh;
    }
    const float boost = (hp && hpn) ? BOOST : 1.0f;
    float m = mask[(size_t)blockIdx.x * POS_PER_BLK + t];
    float contrib = ls * boost * m;

    // block reduction: wave shuffles, thread 0 folds 4 wave sums
#pragma unroll
    for (int off = 32; off > 0; off >>= 1) {
        contrib += __shfl_down(contrib, off, 64);
        m       += __shfl_down(m, off, 64);
    }
    if ((t & 63) == 0) { wl[t >> 6] = contrib; wm[t >> 6] = m; }
    __syncthreads();
    if (t == 0) {
        double Ls = (double)wl[0] + (double)wl[1] + (double)wl[2] + (double)wl[3];
        double Ms = (double)wm[0] + (double)wm[1] + (double)wm[2] + (double)wm[3];
        partials[2 * blockIdx.x]     = Ls;
        partials[2 * blockIdx.x + 1] = Ms;
    }
}

__global__ __launch_bounds__(256) void pal_final(
    const double* __restrict__ partials,
    float*        __restrict__ out)
{
    const int t = threadIdx.x;
    double l = 0.0, m = 0.0;
    for (int i = t; i < NBLK; i += 256) {
        l += partials[2 * i];
        m += partials[2 * i + 1];
    }
    __shared__ double sl[256], sm[256];
    sl[t] = l; sm[t] = m;
    __syncthreads();
    for (int off = 128; off > 0; off >>= 1) {
        if (t < off) { sl[t] += sl[t + off]; sm[t] += sm[t + off]; }
        __syncthreads();
    }
    if (t == 0) out[0] = (float)(sl[0] / sm[0]);
}

extern "C" void kernel_launch(void* const* d_in, const int* in_sizes, int n_in,
                              void* d_out, int out_size, void* d_ws, size_t ws_size,
                              hipStream_t stream) {
    const float* logits = (const float*)d_in[0];
    const int*   labels = (const int*)d_in[1];
    const float* mask   = (const float*)d_in[2];
    float*  out = (float*)d_out;
    double* partials = (double*)d_ws;   // 2*NBLK f64 = 32 KB, fully written before read

    pal_main <<<NBLK, 256, 0, stream>>>(logits, labels, mask, partials);
    pal_final<<<1,    256, 0, stream>>>(partials, out);
}

// Round 6
// 119.533 us; speedup vs baseline: 1.9198x; 1.0204x over previous
//
#include <hip/hip_runtime.h>

// PatternAwareLoss — two-kernel structure, register-prefetch K-body.
// B=64, S=8192, L=24. Blocks of 256 threads handle 256 consecutive positions
// (1536 float4/int4 chunks, perfectly coalesced). 8192/256 = 32 blocks/row,
// so row boundaries align with block boundaries.
// R4 post-mortem: device-scope fence+counter finalize costs ~100 µs on CDNA4
// (non-coherent per-XCD L2) — a second 1-block launch is 20x cheaper.
constexpr int Bdim = 64;
constexpr int S = 8192;
constexpr int L = 24;
constexpr int NPOS = Bdim * S;            // 524288
constexpr int POS_PER_BLK = 256;
constexpr int NBLK = NPOS / POS_PER_BLK;  // 2048
constexpr int BLK_PER_ROW = S / POS_PER_BLK; // 32
constexpr float BOOST = 1.2f;

__device__ __forceinline__ float bce(float x, float y) {
    // max(x,0) - x*y + log1p(exp(-|x|)) with HW transcendentals.
    // __logf arg in (1,2]: rel err ~1e-7; final-scalar impact ~1e-6 vs 0.465 tol.
    float e = __expf(-fabsf(x));
    float l = __logf(1.0f + e);
    return fmaxf(x, 0.0f) - x * y + l;
}

__global__ __launch_bounds__(256) void pal_main(
    const float* __restrict__ logits,
    const int*   __restrict__ labels,
    const float* __restrict__ mask,
    double*      __restrict__ partials)   // [2 * NBLK]
{
    __shared__ float psum[1536];
    __shared__ float plab[1536];
    __shared__ unsigned char hp_next_sh;   // has_punct of position base+256
    __shared__ float wl[4], wm[4];

    const int t = threadIdx.x;
    const size_t cbase = (size_t)blockIdx.x * 1536;   // 16B-chunk base

    // mask value needed in phase 2 — issue its load first so it's in flight
    float m = mask[(size_t)blockIdx.x * POS_PER_BLK + t];

    // ---- phase 1a: prefetch ALL chunks into registers (one vmcnt cluster,
    // not 6 dependent load->use stalls; R4 showed VGPR=20, fully serialized) ----
    float4 lg[6];
    int4   lb[6];
#pragma unroll
    for (int k = 0; k < 6; ++k) {
        const size_t c = cbase + (size_t)t + 256 * k;
        lg[k] = ((const float4*)logits)[c];
        lb[k] = ((const int4*)labels)[c];
    }

    // t==0 peeks next block's first position (96 B) for the boundary boost;
    // forced 0 on the last block of a row (s==S-1 never boosts).
    if (t == 0) {
        int hn = 0;
        if ((blockIdx.x & (BLK_PER_ROW - 1)) != BLK_PER_ROW - 1) {
            const int4* nb = (const int4*)labels + cbase + 1536;
            int sn = 0;
#pragma unroll
            for (int j = 0; j < 6; ++j) { int4 v = nb[j]; sn += v.x + v.y + v.z + v.w; }
            hn = (sn > 0) ? 1 : 0;
        }
        hp_next_sh = (unsigned char)hn;
    }

    // ---- phase 1b: compute per-chunk BCE sums, stage to LDS ----
#pragma unroll
    for (int k = 0; k < 6; ++k) {
        float s = 0.0f;
        s += bce(lg[k].x, (float)lb[k].x);
        s += bce(lg[k].y, (float)lb[k].y);
        s += bce(lg[k].z, (float)lb[k].z);
        s += bce(lg[k].w, (float)lb[k].w);
        psum[t + 256 * k] = s;
        plab[t + 256 * k] = (float)(lb[k].x + lb[k].y + lb[k].z + lb[k].w);
    }
    __syncthreads();

    // ---- phase 2: one position per thread — all 256 threads active ----
    float ls = 0.0f, lab = 0.0f;
#pragma unroll
    for (int j = 0; j < 6; ++j) { ls += psum[6 * t + j]; lab += plab[6 * t + j]; }
    const int hp = (lab > 0.0f);
    int hpn;
    if (t < POS_PER_BLK - 1) {
        float ln = 0.0f;
#pragma unroll
        for (int j = 0; j < 6; ++j) ln += plab[6 * t + 6 + j];
        hpn = (ln > 0.0f);
    } else {
        hpn = hp_next_sh;
    }
    const float boost = (hp && hpn) ? BOOST : 1.0f;
    float contrib = ls * boost * m;

    // block reduction: wave shuffles, thread 0 folds 4 wave sums
#pragma unroll
    for (int off = 32; off > 0; off >>= 1) {
        contrib += __shfl_down(contrib, off, 64);
        m       += __shfl_down(m, off, 64);
    }
    if ((t & 63) == 0) { wl[t >> 6] = contrib; wm[t >> 6] = m; }
    __syncthreads();
    if (t == 0) {
        double Ls = (double)wl[0] + (double)wl[1] + (double)wl[2] + (double)wl[3];
        double Ms = (double)wm[0] + (double)wm[1] + (double)wm[2] + (double)wm[3];
        partials[2 * blockIdx.x]     = Ls;
        partials[2 * blockIdx.x + 1] = Ms;
    }
}

__global__ __launch_bounds__(256) void pal_final(
    const double* __restrict__ partials,
    float*        __restrict__ out)
{
    const int t = threadIdx.x;
    double l = 0.0, m = 0.0;
    for (int i = t; i < NBLK; i += 256) {
        l += partials[2 * i];
        m += partials[2 * i + 1];
    }
    __shared__ double sl[256], sm[256];
    sl[t] = l; sm[t] = m;
    __syncthreads();
    for (int off = 128; off > 0; off >>= 1) {
        if (t < off) { sl[t] += sl[t + off]; sm[t] += sm[t + off]; }
        __syncthreads();
    }
    if (t == 0) out[0] = (float)(sl[0] / sm[0]);
}

extern "C" void kernel_launch(void* const* d_in, const int* in_sizes, int n_in,
                              void* d_out, int out_size, void* d_ws, size_t ws_size,
                              hipStream_t stream) {
    const float* logits = (const float*)d_in[0];
    const int*   labels = (const int*)d_in[1];
    const float* mask   = (const float*)d_in[2];
    float*  out = (float*)d_out;
    double* partials = (double*)d_ws;   // 2*NBLK f64 = 32 KB, fully written before read

    pal_main <<<NBLK, 256, 0, stream>>>(logits, labels, mask, partials);
    pal_final<<<1,    256, 0, stream>>>(partials, out);
}